// Round 2
// baseline (338.961 us; speedup 1.0000x reference)
//
#include <hip/hip_runtime.h>
#include <hip/hip_bf16.h>
#include <stdint.h>

typedef __attribute__((ext_vector_type(8))) __bf16 bf16x8;
typedef __attribute__((ext_vector_type(4))) float f32x4;
typedef __attribute__((ext_vector_type(4))) unsigned int u32x4;
typedef __attribute__((ext_vector_type(4))) unsigned short u16x4;

__device__ __forceinline__ unsigned short f2bf(float f) {
  union { float f; unsigned int u; } v; v.f = f;
  unsigned int r = v.u + 0x7fffu + ((v.u >> 16) & 1u);
  return (unsigned short)(r >> 16);
}

// ---------------- fp32 -> bf16 cast (vectorized) ----------------
__global__ __launch_bounds__(256) void cast_f32_bf16(const float* __restrict__ in,
                                                     unsigned short* __restrict__ out,
                                                     int n) {
  int i = (blockIdx.x * 256 + threadIdx.x) * 4;
  if (i >= n) return;
  f32x4 v = *(const f32x4*)&in[i];
  u16x4 o;
  o[0] = f2bf(v[0]); o[1] = f2bf(v[1]); o[2] = f2bf(v[2]); o[3] = f2bf(v[3]);
  *(u16x4*)&out[i] = o;
}

// ---------------- bf16 GEMM: C[M,N] = A[M,K] * B[N,K]^T ----------------
// 128x128 tile, BK=32, 256 threads (4 waves, each 64x64), 16x16x32 MFMA.
// LDS rows padded to 40 elems (80 B, 16B-aligned, bank stride 20 -> 2-way max).
template<int OUT_BF16>
__global__ __launch_bounds__(256, 2) void gemm_bt(const unsigned short* __restrict__ A,
                                                  const unsigned short* __restrict__ B,
                                                  void* __restrict__ Cv,
                                                  int M, int N, int K) {
  __shared__ unsigned short As[128][40];
  __shared__ unsigned short Bs[128][40];

  const int tid  = threadIdx.x;
  const int lane = tid & 63;
  const int wave = tid >> 6;            // 0..3
  const int wr = (wave >> 1) * 64;      // wave row offset in tile
  const int wc = (wave & 1) * 64;      // wave col offset in tile
  const int row0 = blockIdx.y * 128;
  const int col0 = blockIdx.x * 128;

  const int l16 = lane & 15;
  const int lk  = (lane >> 4) * 8;      // k offset within BK=32

  // staging: idx = tid -> row = tid>>2 (0..63), chunk c = (tid&3)*8
  const int srow = tid >> 2;
  const int sc   = (tid & 3) * 8;

  f32x4 acc[4][4] = {};

  for (int k0 = 0; k0 < K; k0 += 32) {
    __syncthreads();
    u32x4 a0 = *(const u32x4*)&A[(size_t)(row0 + srow) * K + k0 + sc];
    u32x4 a1 = *(const u32x4*)&A[(size_t)(row0 + 64 + srow) * K + k0 + sc];
    u32x4 b0 = *(const u32x4*)&B[(size_t)(col0 + srow) * K + k0 + sc];
    u32x4 b1 = *(const u32x4*)&B[(size_t)(col0 + 64 + srow) * K + k0 + sc];
    *(u32x4*)&As[srow][sc]      = a0;
    *(u32x4*)&As[64 + srow][sc] = a1;
    *(u32x4*)&Bs[srow][sc]      = b0;
    *(u32x4*)&Bs[64 + srow][sc] = b1;
    __syncthreads();

    bf16x8 af[4], bfr[4];
#pragma unroll
    for (int i = 0; i < 4; ++i) af[i]  = *(const bf16x8*)&As[wr + i * 16 + l16][lk];
#pragma unroll
    for (int i = 0; i < 4; ++i) bfr[i] = *(const bf16x8*)&Bs[wc + i * 16 + l16][lk];
#pragma unroll
    for (int i = 0; i < 4; ++i)
#pragma unroll
      for (int j = 0; j < 4; ++j)
        acc[i][j] = __builtin_amdgcn_mfma_f32_16x16x32_bf16(af[i], bfr[j], acc[i][j], 0, 0, 0);
  }

  // epilogue: C/D layout col = lane&15, row = (lane>>4)*4 + r
  const int orow = (lane >> 4) * 4;
#pragma unroll
  for (int i = 0; i < 4; ++i)
#pragma unroll
    for (int j = 0; j < 4; ++j)
#pragma unroll
      for (int r = 0; r < 4; ++r) {
        size_t gr = row0 + wr + i * 16 + orow + r;
        size_t gc = col0 + wc + j * 16 + l16;
        float v = acc[i][j][r];
        if (OUT_BF16) ((unsigned short*)Cv)[gr * N + gc] = f2bf(v);
        else          ((float*)Cv)[gr * N + gc] = v;
      }
}

// ---------------- causal flash attention ----------------
// qkv: [2048][6144] bf16 rows = [q | k | v], head h uses cols h*128..h*128+127
// One block: head h (blockIdx.y), 64 q-rows (blockIdx.x). 4 waves x 16 q-rows.
__global__ __launch_bounds__(256, 2) void attn_kernel(const unsigned short* __restrict__ qkv,
                                                      unsigned short* __restrict__ ctx) {
  __shared__ unsigned short Ks[64][136];    // K tile  [kv][c], pad 136 (272B rows)
  __shared__ unsigned short VTs[128][72];   // V^T     [c][kv], pad 72  (144B rows)
  __shared__ unsigned short Ps[4][16][72];  // per-wave P tile [q][kv]

  const int tid  = threadIdx.x;
  const int lane = tid & 63;
  const int w    = tid >> 6;
  const int h    = blockIdx.y;
  const int qb   = blockIdx.x;
  const int l16  = lane & 15;
  const int lk8  = (lane >> 4) * 8;
  const int qrow = qb * 64 + w * 16;        // wave's q strip base (global)

  // Q fragments (held in registers for the whole kv loop)
  bf16x8 qf[4];
#pragma unroll
  for (int kk = 0; kk < 4; ++kk)
    qf[kk] = *(const bf16x8*)&qkv[(size_t)(qrow + l16) * 6144 + h * 128 + kk * 32 + lk8];

  f32x4 o[8] = {};
  float m[4], lsum[4];
#pragma unroll
  for (int r = 0; r < 4; ++r) { m[r] = -1e30f; lsum[r] = 0.f; }

  const float sscale = 0.08838834764831845f * 1.4426950408889634f;  // 1/sqrt(128)*log2(e)
  const int qg0 = qrow + (lane >> 4) * 4;

  const int nkb = qb + 1;
  for (int kb = 0; kb < nkb; ++kb) {
    __syncthreads();
    // stage K tile [64][128]
#pragma unroll
    for (int it = 0; it < 4; ++it) {
      int idx = it * 256 + tid;
      int row = idx >> 4, c0 = (idx & 15) * 8;
      *(u32x4*)&Ks[row][c0] =
          *(const u32x4*)&qkv[(size_t)(kb * 64 + row) * 6144 + 2048 + h * 128 + c0];
    }
    // stage V^T [128][64] (scalar transpose writes)
#pragma unroll
    for (int it = 0; it < 4; ++it) {
      int idx = it * 256 + tid;
      int t = idx & 63, c0 = (idx >> 6) * 8;
      u32x4 vv = *(const u32x4*)&qkv[(size_t)(kb * 64 + t) * 6144 + 4096 + h * 128 + c0];
      const unsigned short* pv = (const unsigned short*)&vv;
#pragma unroll
      for (int j = 0; j < 8; ++j) VTs[c0 + j][t] = pv[j];
    }
    __syncthreads();

    // S = Q K^T  (16 x 64 per wave)
    f32x4 s[4] = {};
#pragma unroll
    for (int kk = 0; kk < 4; ++kk)
#pragma unroll
      for (int n = 0; n < 4; ++n) {
        bf16x8 kf = *(const bf16x8*)&Ks[n * 16 + l16][kk * 32 + lk8];
        s[n] = __builtin_amdgcn_mfma_f32_16x16x32_bf16(qf[kk], kf, s[n], 0, 0, 0);
      }

    // scale + causal mask + row max
    const bool diag = (kb == qb);
    float rmax[4];
#pragma unroll
    for (int r = 0; r < 4; ++r) rmax[r] = -1e30f;
#pragma unroll
    for (int n = 0; n < 4; ++n) {
      int kg = kb * 64 + n * 16 + l16;
#pragma unroll
      for (int r = 0; r < 4; ++r) {
        float v = s[n][r] * sscale;
        if (diag && kg > qg0 + r) v = -1e30f;
        s[n][r] = v;
        rmax[r] = fmaxf(rmax[r], v);
      }
    }
#pragma unroll
    for (int d = 1; d < 16; d <<= 1)
#pragma unroll
      for (int r = 0; r < 4; ++r) rmax[r] = fmaxf(rmax[r], __shfl_xor(rmax[r], d));

    float alpha[4];
#pragma unroll
    for (int r = 0; r < 4; ++r) {
      float mn = fmaxf(m[r], rmax[r]);
      alpha[r] = exp2f(m[r] - mn);
      m[r] = mn;
    }
    float rsum[4] = {0.f, 0.f, 0.f, 0.f};
#pragma unroll
    for (int n = 0; n < 4; ++n)
#pragma unroll
      for (int r = 0; r < 4; ++r) {
        float p = exp2f(s[n][r] - m[r]);
        s[n][r] = p;
        rsum[r] += p;
      }
#pragma unroll
    for (int d = 1; d < 16; d <<= 1)
#pragma unroll
      for (int r = 0; r < 4; ++r) rsum[r] += __shfl_xor(rsum[r], d);
#pragma unroll
    for (int r = 0; r < 4; ++r) lsum[r] = lsum[r] * alpha[r] + rsum[r];

    // rescale O
#pragma unroll
    for (int n = 0; n < 8; ++n)
#pragma unroll
      for (int r = 0; r < 4; ++r) o[n][r] *= alpha[r];

    // P -> LDS (bf16)
#pragma unroll
    for (int n = 0; n < 4; ++n)
#pragma unroll
      for (int r = 0; r < 4; ++r)
        Ps[w][(lane >> 4) * 4 + r][n * 16 + l16] = f2bf(s[n][r]);
    __syncthreads();

    // O += P V   (A = P [16x64], B = V^T[c][kv] frags)
#pragma unroll
    for (int kk = 0; kk < 2; ++kk) {
      bf16x8 pf = *(const bf16x8*)&Ps[w][l16][kk * 32 + lk8];
#pragma unroll
      for (int n = 0; n < 8; ++n) {
        bf16x8 vf = *(const bf16x8*)&VTs[n * 16 + l16][kk * 32 + lk8];
        o[n] = __builtin_amdgcn_mfma_f32_16x16x32_bf16(pf, vf, o[n], 0, 0, 0);
      }
    }
  }

  // epilogue: ctx[t][h*128 + c] = O / l
#pragma unroll
  for (int r = 0; r < 4; ++r) {
    float inv = 1.0f / lsum[r];
    size_t gr = qrow + (lane >> 4) * 4 + r;
#pragma unroll
    for (int n = 0; n < 8; ++n)
      ctx[gr * 2048 + h * 128 + n * 16 + l16] = f2bf(o[n][r] * inv);
  }
}

// ---------------- launch ----------------
extern "C" void kernel_launch(void* const* d_in, const int* in_sizes, int n_in,
                              void* d_out, int out_size, void* d_ws, size_t ws_size,
                              hipStream_t stream) {
  const float* x  = (const float*)d_in[0];
  const float* Wa = (const float*)d_in[1];
  const float* Wp = (const float*)d_in[2];
  float* out = (float*)d_out;

  char* ws = (char*)d_ws;
  unsigned short* xb   = (unsigned short*)(ws);                       // 8 MB
  unsigned short* wab  = (unsigned short*)(ws + 8388608);             // 24 MB
  unsigned short* wpb  = (unsigned short*)(ws + 33554432);            // 8 MB
  unsigned short* qkvb = (unsigned short*)(ws + 41943040);            // 24 MB
  unsigned short* ctx  = (unsigned short*)(ws + 67108864);            // 8 MB

  cast_f32_bf16<<<4096, 256, 0, stream>>>(x, xb, 2048 * 2048);
  cast_f32_bf16<<<12288, 256, 0, stream>>>(Wa, wab, 6144 * 2048);
  cast_f32_bf16<<<4096, 256, 0, stream>>>(Wp, wpb, 2048 * 2048);

  // qkv = x @ W_attn^T : [2048, 6144]
  gemm_bt<1><<<dim3(48, 16), 256, 0, stream>>>(xb, wab, qkvb, 2048, 6144, 2048);

  // causal multi-head attention -> ctx [2048, 2048] bf16
  attn_kernel<<<dim3(32, 16), 256, 0, stream>>>(qkvb, ctx);

  // out = ctx @ W_proj^T : [2048, 2048] fp32
  gemm_bt<0><<<dim3(16, 16), 256, 0, stream>>>(ctx, wpb, out, 2048, 2048, 2048);
}

// Round 5
// 313.032 us; speedup vs baseline: 1.0828x; 1.0828x over previous
//
#include <hip/hip_runtime.h>
#include <hip/hip_bf16.h>
#include <stdint.h>

typedef __attribute__((ext_vector_type(8))) __bf16 bf16x8;
typedef __attribute__((ext_vector_type(4))) float f32x4;
typedef __attribute__((ext_vector_type(4))) unsigned int u32x4;
typedef __attribute__((ext_vector_type(4))) unsigned short u16x4;

__device__ __forceinline__ unsigned short f2bf(float f) {
  union { float f; unsigned int u; } v; v.f = f;
  unsigned int r = v.u + 0x7fffu + ((v.u >> 16) & 1u);
  return (unsigned short)(r >> 16);
}

// async global->LDS, 16B per lane. LDS dest = wave-uniform base + lane*16.
__device__ __forceinline__ void gload_lds16(const void* g, void* l) {
  __builtin_amdgcn_global_load_lds(
      (const __attribute__((address_space(1))) unsigned int*)g,
      (__attribute__((address_space(3))) unsigned int*)l, 16, 0, 0);
}

// ---------------- fp32 -> bf16 cast (vectorized) ----------------
__global__ __launch_bounds__(256) void cast_f32_bf16(const float* __restrict__ in,
                                                     unsigned short* __restrict__ out,
                                                     int n) {
  int i = (blockIdx.x * 256 + threadIdx.x) * 4;
  if (i >= n) return;
  f32x4 v = *(const f32x4*)&in[i];
  u16x4 o;
  o[0] = f2bf(v[0]); o[1] = f2bf(v[1]); o[2] = f2bf(v[2]); o[3] = f2bf(v[3]);
  *(u16x4*)&out[i] = o;
}

// ---------------- bf16 GEMM: C[M,N] = A[M,K] * B[N,K]^T ----------------
// m97 structure: 128x128 tile, BK=32, 4 waves, linear LDS + global_load_lds w=16.
template<int OUT_BF16>
__global__ __launch_bounds__(256) void gemm_bt(const unsigned short* __restrict__ A,
                                               const unsigned short* __restrict__ B,
                                               void* __restrict__ Cv,
                                               int M, int N, int K) {
  __shared__ unsigned short As[128 * 32];   // linear row-major [128][32]
  __shared__ unsigned short Bs[128 * 32];

  const int tid  = threadIdx.x;
  const int lane = tid & 63;
  const int wave = tid >> 6;            // 0..3
  const int wr = (wave >> 1) * 64;
  const int wc = (wave & 1) * 64;
  const int row0 = blockIdx.y * 128;
  const int col0 = blockIdx.x * 128;
  const int l16 = lane & 15;
  const int lk  = (lane >> 4) * 8;

  // staging: instr t (= wave*2+i) covers LDS rows t*16..t*16+15.
  // lane l -> row t*16 + (l>>2), col chunk (l&3)*8  (matches linear dest + lane*16)
  const int srow = lane >> 2;
  const int sc   = (lane & 3) * 8;

  f32x4 acc[4][4] = {};

  for (int k0 = 0; k0 < K; k0 += 32) {
    __syncthreads();
#pragma unroll
    for (int i = 0; i < 2; ++i) {
      int t = wave * 2 + i;
      int r = t * 16 + srow;
      gload_lds16(&A[(size_t)(row0 + r) * K + k0 + sc], &As[t * 512]);
      gload_lds16(&B[(size_t)(col0 + r) * K + k0 + sc], &Bs[t * 512]);
    }
    __syncthreads();   // compiler emits vmcnt(0) drain here

    bf16x8 af[4], bfr[4];
#pragma unroll
    for (int i = 0; i < 4; ++i) af[i]  = *(const bf16x8*)&As[(wr + i * 16 + l16) * 32 + lk];
#pragma unroll
    for (int i = 0; i < 4; ++i) bfr[i] = *(const bf16x8*)&Bs[(wc + i * 16 + l16) * 32 + lk];
#pragma unroll
    for (int i = 0; i < 4; ++i)
#pragma unroll
      for (int j = 0; j < 4; ++j)
        acc[i][j] = __builtin_amdgcn_mfma_f32_16x16x32_bf16(af[i], bfr[j], acc[i][j], 0, 0, 0);
  }

  // epilogue: C/D layout col = lane&15, row = (lane>>4)*4 + r
  const int orow = (lane >> 4) * 4;
#pragma unroll
  for (int i = 0; i < 4; ++i)
#pragma unroll
    for (int j = 0; j < 4; ++j)
#pragma unroll
      for (int r = 0; r < 4; ++r) {
        size_t gr = row0 + wr + i * 16 + orow + r;
        size_t gc = col0 + wc + j * 16 + l16;
        float v = acc[i][j][r];
        if (OUT_BF16) ((unsigned short*)Cv)[gr * N + gc] = f2bf(v);
        else          ((float*)Cv)[gr * N + gc] = v;
      }
}

// ---------------- causal flash attention ----------------
// qkv: [2048][6144] bf16 rows = [q | k | v], head h uses cols h*128..+127
// One block: 64 q-rows of one head; 4 waves x 16 q-rows.
// (h,qb) remapped so co-resident blocks (flat, flat+256) have complementary work.
__global__ __launch_bounds__(256, 2) void attn_kernel(const unsigned short* __restrict__ qkv,
                                                      unsigned short* __restrict__ ctx) {
  __shared__ unsigned short Ks[64][136];    // K tile  [kv][c]
  __shared__ unsigned short VTs[128][72];   // V^T     [c][kv]
  __shared__ unsigned short Ps[4][16][72];  // per-wave P tile [q][kv]

  const int tid  = threadIdx.x;
  const int lane = tid & 63;
  const int w    = tid >> 6;
  const int l16  = lane & 15;
  const int lk8  = (lane >> 4) * 8;

  // balanced (h, qb) mapping: flat<256 -> qb ascending (heads 0-7),
  // flat>=256 -> qb descending (heads 8-15); CU gets flat & flat+256 -> 33 iters.
  const int flat = blockIdx.x + blockIdx.y * 32;
  int h, qb;
  if (flat < 256) { h = flat >> 5; qb = flat & 31; }
  else            { int f2 = flat - 256; h = 8 + (f2 >> 5); qb = 31 - (f2 & 31); }

  const int qrow = qb * 64 + w * 16;

  // Q fragments (registers for whole kv loop)
  bf16x8 qf[4];
#pragma unroll
  for (int kk = 0; kk < 4; ++kk)
    qf[kk] = *(const bf16x8*)&qkv[(size_t)(qrow + l16) * 6144 + h * 128 + kk * 32 + lk8];

  f32x4 o[8] = {};
  float m[4], lsum[4];
#pragma unroll
  for (int r = 0; r < 4; ++r) { m[r] = -1e30f; lsum[r] = 0.f; }

  const float sscale = 0.08838834764831845f * 1.4426950408889634f;  // 1/sqrt(128)*log2e
  const int qg0 = qrow + (lane >> 4) * 4;

  // V^T staging assignment: thread owns rows t0v..t0v+3, cols c0v..c0v+7
  const int t0v = (tid & 15) * 4;
  const int c0v = (tid >> 4) * 8;

  const int nkb = qb + 1;
  for (int kb = 0; kb < nkb; ++kb) {
    // T14-lite: issue K/V global loads to regs BEFORE the barrier
    u32x4 kreg[4], vreg[4];
#pragma unroll
    for (int it = 0; it < 4; ++it) {
      int idx = it * 256 + tid;
      int row = idx >> 4, c0 = (idx & 15) * 8;
      kreg[it] = *(const u32x4*)&qkv[(size_t)(kb * 64 + row) * 6144 + 2048 + h * 128 + c0];
    }
#pragma unroll
    for (int r = 0; r < 4; ++r)
      vreg[r] = *(const u32x4*)&qkv[(size_t)(kb * 64 + t0v + r) * 6144 + 4096 + h * 128 + c0v];

    __syncthreads();   // previous iteration's LDS reads complete

    // K tile [64][128]
#pragma unroll
    for (int it = 0; it < 4; ++it) {
      int idx = it * 256 + tid;
      int row = idx >> 4, c0 = (idx & 15) * 8;
      *(u32x4*)&Ks[row][c0] = kreg[it];
    }
    // V^T [128][64]: register transpose, b64 writes (4x fewer LDS ops)
    {
      const unsigned short* p0 = (const unsigned short*)&vreg[0];
      const unsigned short* p1 = (const unsigned short*)&vreg[1];
      const unsigned short* p2 = (const unsigned short*)&vreg[2];
      const unsigned short* p3 = (const unsigned short*)&vreg[3];
#pragma unroll
      for (int j = 0; j < 8; ++j) {
        u16x4 wv; wv[0] = p0[j]; wv[1] = p1[j]; wv[2] = p2[j]; wv[3] = p3[j];
        *(u16x4*)&VTs[c0v + j][t0v] = wv;
      }
    }
    __syncthreads();

    // S = Q K^T (16x64 per wave)
    f32x4 s[4] = {};
#pragma unroll
    for (int kk = 0; kk < 4; ++kk)
#pragma unroll
      for (int n = 0; n < 4; ++n) {
        bf16x8 kf = *(const bf16x8*)&Ks[n * 16 + l16][kk * 32 + lk8];
        s[n] = __builtin_amdgcn_mfma_f32_16x16x32_bf16(qf[kk], kf, s[n], 0, 0, 0);
      }

    // scale + causal mask + row max
    const bool diag = (kb == qb);
    float rmax[4];
#pragma unroll
    for (int r = 0; r < 4; ++r) rmax[r] = -1e30f;
#pragma unroll
    for (int n = 0; n < 4; ++n) {
      int kg = kb * 64 + n * 16 + l16;
#pragma unroll
      for (int r = 0; r < 4; ++r) {
        float v = s[n][r] * sscale;
        if (diag && kg > qg0 + r) v = -1e30f;
        s[n][r] = v;
        rmax[r] = fmaxf(rmax[r], v);
      }
    }
#pragma unroll
    for (int d = 1; d < 16; d <<= 1)
#pragma unroll
      for (int r = 0; r < 4; ++r) rmax[r] = fmaxf(rmax[r], __shfl_xor(rmax[r], d));

    float alpha[4];
#pragma unroll
    for (int r = 0; r < 4; ++r) {
      float mn = fmaxf(m[r], rmax[r]);
      alpha[r] = exp2f(m[r] - mn);
      m[r] = mn;
    }
    float rsum[4] = {0.f, 0.f, 0.f, 0.f};
#pragma unroll
    for (int n = 0; n < 4; ++n)
#pragma unroll
      for (int r = 0; r < 4; ++r) {
        float p = exp2f(s[n][r] - m[r]);
        s[n][r] = p;
        rsum[r] += p;
      }
#pragma unroll
    for (int d = 1; d < 16; d <<= 1)
#pragma unroll
      for (int r = 0; r < 4; ++r) rsum[r] += __shfl_xor(rsum[r], d);
#pragma unroll
    for (int r = 0; r < 4; ++r) lsum[r] = lsum[r] * alpha[r] + rsum[r];

    // rescale O
#pragma unroll
    for (int n = 0; n < 8; ++n)
#pragma unroll
      for (int r = 0; r < 4; ++r) o[n][r] *= alpha[r];

    // P -> LDS (bf16)
#pragma unroll
    for (int n = 0; n < 4; ++n)
#pragma unroll
      for (int r = 0; r < 4; ++r)
        Ps[w][(lane >> 4) * 4 + r][n * 16 + l16] = f2bf(s[n][r]);
    __syncthreads();

    // O += P V
#pragma unroll
    for (int kk = 0; kk < 2; ++kk) {
      bf16x8 pf = *(const bf16x8*)&Ps[w][l16][kk * 32 + lk8];
#pragma unroll
      for (int n = 0; n < 8; ++n) {
        bf16x8 vf = *(const bf16x8*)&VTs[n * 16 + l16][kk * 32 + lk8];
        o[n] = __builtin_amdgcn_mfma_f32_16x16x32_bf16(pf, vf, o[n], 0, 0, 0);
      }
    }
  }

  // epilogue
#pragma unroll
  for (int r = 0; r < 4; ++r) {
    float inv = 1.0f / lsum[r];
    size_t gr = qrow + (lane >> 4) * 4 + r;
#pragma unroll
    for (int n = 0; n < 8; ++n)
      ctx[gr * 2048 + h * 128 + n * 16 + l16] = f2bf(o[n][r] * inv);
  }
}

// ---------------- launch ----------------
extern "C" void kernel_launch(void* const* d_in, const int* in_sizes, int n_in,
                              void* d_out, int out_size, void* d_ws, size_t ws_size,
                              hipStream_t stream) {
  const float* x  = (const float*)d_in[0];
  const float* Wa = (const float*)d_in[1];
  const float* Wp = (const float*)d_in[2];
  float* out = (float*)d_out;

  char* ws = (char*)d_ws;
  unsigned short* xb   = (unsigned short*)(ws);                       // 8 MB
  unsigned short* wab  = (unsigned short*)(ws + 8388608);             // 24 MB
  unsigned short* wpb  = (unsigned short*)(ws + 33554432);            // 8 MB
  unsigned short* qkvb = (unsigned short*)(ws + 41943040);            // 24 MB
  unsigned short* ctx  = (unsigned short*)(ws + 67108864);            // 8 MB

  cast_f32_bf16<<<4096, 256, 0, stream>>>(x, xb, 2048 * 2048);
  cast_f32_bf16<<<12288, 256, 0, stream>>>(Wa, wab, 6144 * 2048);
  cast_f32_bf16<<<4096, 256, 0, stream>>>(Wp, wpb, 2048 * 2048);

  // qkv = x @ W_attn^T : [2048, 6144]
  gemm_bt<1><<<dim3(48, 16), 256, 0, stream>>>(xb, wab, qkvb, 2048, 6144, 2048);

  // causal multi-head attention -> ctx [2048, 2048] bf16
  attn_kernel<<<dim3(32, 16), 256, 0, stream>>>(qkvb, ctx);

  // out = ctx @ W_proj^T : [2048, 2048] fp32
  gemm_bt<0><<<dim3(16, 16), 256, 0, stream>>>(ctx, wpb, out, 2048, 2048, 2048);
}

// Round 6
// 300.972 us; speedup vs baseline: 1.1262x; 1.0401x over previous
//
#include <hip/hip_runtime.h>
#include <hip/hip_bf16.h>
#include <stdint.h>

typedef __attribute__((ext_vector_type(8))) __bf16 bf16x8;
typedef __attribute__((ext_vector_type(4))) float f32x4;
typedef __attribute__((ext_vector_type(4))) unsigned int u32x4;
typedef __attribute__((ext_vector_type(4))) unsigned short u16x4;

__device__ __forceinline__ unsigned short f2bf(float f) {
  union { float f; unsigned int u; } v; v.f = f;
  unsigned int r = v.u + 0x7fffu + ((v.u >> 16) & 1u);
  return (unsigned short)(r >> 16);
}

// async global->LDS, 16B per lane. LDS dest = wave-uniform base + lane*16.
__device__ __forceinline__ void gload_lds16(const void* g, void* l) {
  __builtin_amdgcn_global_load_lds(
      (const __attribute__((address_space(1))) unsigned int*)g,
      (__attribute__((address_space(3))) unsigned int*)l, 16, 0, 0);
}

// ---------------- fp32 -> bf16 cast (vectorized) ----------------
__global__ __launch_bounds__(256) void cast_f32_bf16(const float* __restrict__ in,
                                                     unsigned short* __restrict__ out,
                                                     int n) {
  int i = (blockIdx.x * 256 + threadIdx.x) * 4;
  if (i >= n) return;
  f32x4 v = *(const f32x4*)&in[i];
  u16x4 o;
  o[0] = f2bf(v[0]); o[1] = f2bf(v[1]); o[2] = f2bf(v[2]); o[3] = f2bf(v[3]);
  *(u16x4*)&out[i] = o;
}

// ---------------- bf16 GEMM: C[M,N] = A[M,K] * B[N,K]^T ----------------
// 128x128 tile, BK=32, 4 waves. 2-phase double-buffered global_load_lds:
// stage(next) issued BEFORE compute(cur); ONE barrier/iter at the end
// (its vmcnt(0) drain comes after MFMA, so stage latency is hidden).
template<int OUT_BF16>
__global__ __launch_bounds__(256) void gemm_bt(const unsigned short* __restrict__ A,
                                               const unsigned short* __restrict__ B,
                                               void* __restrict__ Cv,
                                               int M, int N, int K) {
  __shared__ unsigned short As[2][128 * 32];
  __shared__ unsigned short Bs[2][128 * 32];

  const int tid  = threadIdx.x;
  const int lane = tid & 63;
  const int wave = tid >> 6;            // 0..3
  const int wr = (wave >> 1) * 64;
  const int wc = (wave & 1) * 64;
  const int row0 = blockIdx.y * 128;
  const int col0 = blockIdx.x * 128;
  const int l16 = lane & 15;
  const int lk  = (lane >> 4) * 8;

  // staging: instr t (= wave*2+i) covers LDS rows t*16..t*16+15.
  // lane l -> row t*16 + (l>>2), chunk (l&3)*8 (matches linear dest + lane*16)
  const int srow = lane >> 2;
  const int sc   = (lane & 3) * 8;

  f32x4 acc[4][4] = {};

  // prologue: fill buffer 0
#pragma unroll
  for (int i = 0; i < 2; ++i) {
    int t = wave * 2 + i;
    int r = t * 16 + srow;
    gload_lds16(&A[(size_t)(row0 + r) * K + sc], &As[0][t * 512]);
    gload_lds16(&B[(size_t)(col0 + r) * K + sc], &Bs[0][t * 512]);
  }
  __syncthreads();

  int cur = 0;
  for (int k0 = 0; k0 < K; k0 += 32, cur ^= 1) {
    // issue next-tile stage first (overlaps with this tile's compute)
    if (k0 + 32 < K) {
#pragma unroll
      for (int i = 0; i < 2; ++i) {
        int t = wave * 2 + i;
        int r = t * 16 + srow;
        gload_lds16(&A[(size_t)(row0 + r) * K + k0 + 32 + sc], &As[cur ^ 1][t * 512]);
        gload_lds16(&B[(size_t)(col0 + r) * K + k0 + 32 + sc], &Bs[cur ^ 1][t * 512]);
      }
    }

    bf16x8 af[4], bfr[4];
#pragma unroll
    for (int i = 0; i < 4; ++i) af[i]  = *(const bf16x8*)&As[cur][(wr + i * 16 + l16) * 32 + lk];
#pragma unroll
    for (int i = 0; i < 4; ++i) bfr[i] = *(const bf16x8*)&Bs[cur][(wc + i * 16 + l16) * 32 + lk];
#pragma unroll
    for (int i = 0; i < 4; ++i)
#pragma unroll
      for (int j = 0; j < 4; ++j)
        acc[i][j] = __builtin_amdgcn_mfma_f32_16x16x32_bf16(af[i], bfr[j], acc[i][j], 0, 0, 0);

    __syncthreads();  // vmcnt(0)+lgkmcnt(0) drain: next buffer ready, cur reads done
  }

  // epilogue: C/D layout col = lane&15, row = (lane>>4)*4 + r
  const int orow = (lane >> 4) * 4;
#pragma unroll
  for (int i = 0; i < 4; ++i)
#pragma unroll
    for (int j = 0; j < 4; ++j)
#pragma unroll
      for (int r = 0; r < 4; ++r) {
        size_t gr = row0 + wr + i * 16 + orow + r;
        size_t gc = col0 + wc + j * 16 + l16;
        float v = acc[i][j][r];
        if (OUT_BF16) ((unsigned short*)Cv)[gr * N + gc] = f2bf(v);
        else          ((float*)Cv)[gr * N + gc] = v;
      }
}

// ---------------- causal flash attention ----------------
// qkv: [2048][6144] bf16 rows = [q | k | v], head h uses cols h*128..+127
// One block: 64 q-rows of one head; 4 waves x 16 q-rows.
// T2 XOR-swizzled LDS tiles (read-side was an ~8-way conflict with padded rows).
#define KS_IDX(r, c) ((((r) * 128) + (c)) ^ (((r) & 7) << 3))
#define VT_IDX(c, t) ((((c) * 64)  + (t)) ^ (((c) & 7) << 3))
#define PS_IDX(q, c) ((((q) * 64)  + (c)) ^ (((q) & 7) << 3))

__global__ __launch_bounds__(256, 2) void attn_kernel(const unsigned short* __restrict__ qkv,
                                                      unsigned short* __restrict__ ctx) {
  __shared__ unsigned short Ks[64 * 128];    // K tile  [kv][c], swizzled
  __shared__ unsigned short VTs[128 * 64];   // V^T     [c][kv], swizzled
  __shared__ unsigned short Ps[4][16 * 64];  // per-wave P tile [q][kv], swizzled

  const int tid  = threadIdx.x;
  const int lane = tid & 63;
  const int w    = tid >> 6;
  const int l16  = lane & 15;
  const int lk8  = (lane >> 4) * 8;

  // balanced (h, qb) mapping: co-resident blocks (flat, flat+256) get
  // complementary qb -> every CU-pair does 33 kv-iters.
  const int flat = blockIdx.x + blockIdx.y * 32;
  int h, qb;
  if (flat < 256) { h = flat >> 5; qb = flat & 31; }
  else            { int f2 = flat - 256; h = 8 + (f2 >> 5); qb = 31 - (f2 & 31); }

  const int qrow = qb * 64 + w * 16;

  // Q fragments (registers for whole kv loop)
  bf16x8 qf[4];
#pragma unroll
  for (int kk = 0; kk < 4; ++kk)
    qf[kk] = *(const bf16x8*)&qkv[(size_t)(qrow + l16) * 6144 + h * 128 + kk * 32 + lk8];

  f32x4 o[8] = {};
  float m[4], lsum[4];
#pragma unroll
  for (int r = 0; r < 4; ++r) { m[r] = -1e30f; lsum[r] = 0.f; }

  const float sscale = 0.08838834764831845f * 1.4426950408889634f;  // 1/sqrt(128)*log2e
  const int qg0 = qrow + (lane >> 4) * 4;

  // V^T staging: thread owns rows t0v..t0v+3 (kv), cols c0v..c0v+7 (channel)
  const int t0v = (tid & 15) * 4;
  const int c0v = (tid >> 4) * 8;

  const int nkb = qb + 1;
  for (int kb = 0; kb < nkb; ++kb) {
    // issue K/V global loads to regs BEFORE the barrier (latency overlap)
    u32x4 kreg[4], vreg[4];
#pragma unroll
    for (int it = 0; it < 4; ++it) {
      int idx = it * 256 + tid;
      int row = idx >> 4, c0 = (idx & 15) * 8;
      kreg[it] = *(const u32x4*)&qkv[(size_t)(kb * 64 + row) * 6144 + 2048 + h * 128 + c0];
    }
#pragma unroll
    for (int r = 0; r < 4; ++r)
      vreg[r] = *(const u32x4*)&qkv[(size_t)(kb * 64 + t0v + r) * 6144 + 4096 + h * 128 + c0v];

    __syncthreads();   // previous iteration's LDS reads complete

    // K tile [64][128] swizzled
#pragma unroll
    for (int it = 0; it < 4; ++it) {
      int idx = it * 256 + tid;
      int row = idx >> 4, c0 = (idx & 15) * 8;
      *(u32x4*)&Ks[KS_IDX(row, c0)] = kreg[it];
    }
    // V^T [128][64] swizzled: register transpose, b64 writes
    {
      const unsigned short* p0 = (const unsigned short*)&vreg[0];
      const unsigned short* p1 = (const unsigned short*)&vreg[1];
      const unsigned short* p2 = (const unsigned short*)&vreg[2];
      const unsigned short* p3 = (const unsigned short*)&vreg[3];
#pragma unroll
      for (int j = 0; j < 8; ++j) {
        u16x4 wv; wv[0] = p0[j]; wv[1] = p1[j]; wv[2] = p2[j]; wv[3] = p3[j];
        *(u16x4*)&VTs[VT_IDX(c0v + j, t0v)] = wv;
      }
    }
    __syncthreads();

    // S = Q K^T (16x64 per wave)
    f32x4 s[4] = {};
#pragma unroll
    for (int kk = 0; kk < 4; ++kk)
#pragma unroll
      for (int n = 0; n < 4; ++n) {
        bf16x8 kf = *(const bf16x8*)&Ks[KS_IDX(n * 16 + l16, kk * 32 + lk8)];
        s[n] = __builtin_amdgcn_mfma_f32_16x16x32_bf16(qf[kk], kf, s[n], 0, 0, 0);
      }

    // scale + causal mask + row max
    const bool diag = (kb == qb);
    float rmax[4];
#pragma unroll
    for (int r = 0; r < 4; ++r) rmax[r] = -1e30f;
#pragma unroll
    for (int n = 0; n < 4; ++n) {
      int kg = kb * 64 + n * 16 + l16;
#pragma unroll
      for (int r = 0; r < 4; ++r) {
        float v = s[n][r] * sscale;
        if (diag && kg > qg0 + r) v = -1e30f;
        s[n][r] = v;
        rmax[r] = fmaxf(rmax[r], v);
      }
    }
#pragma unroll
    for (int d = 1; d < 16; d <<= 1)
#pragma unroll
      for (int r = 0; r < 4; ++r) rmax[r] = fmaxf(rmax[r], __shfl_xor(rmax[r], d));

    float alpha[4];
#pragma unroll
    for (int r = 0; r < 4; ++r) {
      float mn = fmaxf(m[r], rmax[r]);
      alpha[r] = exp2f(m[r] - mn);
      m[r] = mn;
    }
    float rsum[4] = {0.f, 0.f, 0.f, 0.f};
#pragma unroll
    for (int n = 0; n < 4; ++n)
#pragma unroll
      for (int r = 0; r < 4; ++r) {
        float p = exp2f(s[n][r] - m[r]);
        s[n][r] = p;
        rsum[r] += p;
      }
#pragma unroll
    for (int d = 1; d < 16; d <<= 1)
#pragma unroll
      for (int r = 0; r < 4; ++r) rsum[r] += __shfl_xor(rsum[r], d);
#pragma unroll
    for (int r = 0; r < 4; ++r) lsum[r] = lsum[r] * alpha[r] + rsum[r];

    // rescale O
#pragma unroll
    for (int n = 0; n < 8; ++n)
#pragma unroll
      for (int r = 0; r < 4; ++r) o[n][r] *= alpha[r];

    // P -> LDS (wave-private slice: no barrier needed, only lgkm drain)
#pragma unroll
    for (int n = 0; n < 4; ++n)
#pragma unroll
      for (int r = 0; r < 4; ++r)
        Ps[w][PS_IDX((lane >> 4) * 4 + r, n * 16 + l16)] = f2bf(s[n][r]);
    asm volatile("s_waitcnt lgkmcnt(0)" ::: "memory");

    // O += P V
#pragma unroll
    for (int kk = 0; kk < 2; ++kk) {
      bf16x8 pf = *(const bf16x8*)&Ps[w][PS_IDX(l16, kk * 32 + lk8)];
#pragma unroll
      for (int n = 0; n < 8; ++n) {
        bf16x8 vf = *(const bf16x8*)&VTs[VT_IDX(n * 16 + l16, kk * 32 + lk8)];
        o[n] = __builtin_amdgcn_mfma_f32_16x16x32_bf16(pf, vf, o[n], 0, 0, 0);
      }
    }
  }

  // epilogue
#pragma unroll
  for (int r = 0; r < 4; ++r) {
    float inv = 1.0f / lsum[r];
    size_t gr = qrow + (lane >> 4) * 4 + r;
#pragma unroll
    for (int n = 0; n < 8; ++n)
      ctx[gr * 2048 + h * 128 + n * 16 + l16] = f2bf(o[n][r] * inv);
  }
}

// ---------------- launch ----------------
extern "C" void kernel_launch(void* const* d_in, const int* in_sizes, int n_in,
                              void* d_out, int out_size, void* d_ws, size_t ws_size,
                              hipStream_t stream) {
  const float* x  = (const float*)d_in[0];
  const float* Wa = (const float*)d_in[1];
  const float* Wp = (const float*)d_in[2];
  float* out = (float*)d_out;

  char* ws = (char*)d_ws;
  unsigned short* xb   = (unsigned short*)(ws);                       // 8 MB
  unsigned short* wab  = (unsigned short*)(ws + 8388608);             // 24 MB
  unsigned short* wpb  = (unsigned short*)(ws + 33554432);            // 8 MB
  unsigned short* qkvb = (unsigned short*)(ws + 41943040);            // 24 MB
  unsigned short* ctx  = (unsigned short*)(ws + 67108864);            // 8 MB

  cast_f32_bf16<<<4096, 256, 0, stream>>>(x, xb, 2048 * 2048);
  cast_f32_bf16<<<12288, 256, 0, stream>>>(Wa, wab, 6144 * 2048);
  cast_f32_bf16<<<4096, 256, 0, stream>>>(Wp, wpb, 2048 * 2048);

  // qkv = x @ W_attn^T : [2048, 6144]
  gemm_bt<1><<<dim3(48, 16), 256, 0, stream>>>(xb, wab, qkvb, 2048, 6144, 2048);

  // causal multi-head attention -> ctx [2048, 2048] bf16
  attn_kernel<<<dim3(32, 16), 256, 0, stream>>>(qkvb, ctx);

  // out = ctx @ W_proj^T : [2048, 2048] fp32
  gemm_bt<0><<<dim3(16, 16), 256, 0, stream>>>(ctx, wpb, out, 2048, 2048, 2048);
}